// Round 9
// baseline (370.895 us; speedup 1.0000x reference)
//
#include <hip/hip_runtime.h>
#include <hip/hip_bf16.h>

#define EW 640
#define EH 480
#define NVOX (2 * EH * EW)     // 614400 voxels
#define NWORDS (NVOX / 32)     // 19200 uint32 words = 76800 B bitmap
#define BLK 1024               // 16 waves
#define GRID 256               // 1 block/CU
#define WAVES 16
#define CHUNK 64               // events per chunk (1 KB, one DMA instr/wave)
#define DEPTH 4                // chunks in flight per wave

typedef float vf4 __attribute__((ext_vector_type(4)));

__device__ __forceinline__ int ev_idx(vf4 e) {
    // idx = x + W*y + W*H*((p+1)/2); exact in fp32 (all values < 2^24)
    float p01 = (e.w + 1.0f) * 0.5f;   // {-1,1} -> {0,1}
    return (int)(e.x + (float)EW * e.y + (float)(EW * EH) * p01);
}

// Async global->LDS DMA, 16 B per lane. LDS dest is wave-uniform base +
// lane*16 (m104/m108); completion tracked by vmcnt.
__device__ __forceinline__ void async_ev16(const vf4* g, vf4* l) {
    __builtin_amdgcn_global_load_lds(
        (__attribute__((address_space(1))) void*)g,
        (__attribute__((address_space(3))) void*)l,
        16, 0, 0);
}

// R8 lesson: the VGPR-path read stream is pinned at ~2.4 TB/s regardless of
// occupancy (16 vs 32 w/CU) and ILP (4 vs 8) -> per-CU outstanding-line cap.
// This kernel streams events through the global_load_lds DMA path instead:
// per-wave private 4-deep chunk pipeline (64 KB/CU in flight), hand-rolled
// vmcnt(3) waits. Bitmap + merge identical to R8 (proven correct & cheap).
__global__ void __launch_bounds__(BLK, 4)
event_bitmap_dma(const vf4* __restrict__ events,
                 unsigned int* __restrict__ gbm, int n) {
    __shared__ unsigned int bm[NWORDS];                  // 76.8 KB
    __shared__ vf4 stage[WAVES * DEPTH * CHUNK];         // 64 KB (139 KB total)

    for (int w = threadIdx.x; w < NWORDS; w += BLK) bm[w] = 0u;
    __syncthreads();   // stage bufs are per-wave private: no sync needed there

    const int wave = threadIdx.x >> 6;
    const int lane = threadIdx.x & 63;
    const int gw = blockIdx.x * WAVES + wave;            // [0, 4096)
    const int per_wave = n / (GRID * WAVES);             // 4096 for N=2^24
    const int nchunks = per_wave / CHUNK;                // 64
    const vf4* base = events + (size_t)gw * per_wave + lane;
    vf4* bufs = &stage[wave * DEPTH * CHUNK];

    const int pro = nchunks < DEPTH ? nchunks : DEPTH;
    for (int c = 0; c < pro; ++c)
        async_ev16(base + c * CHUNK, &bufs[c * CHUNK]);

    for (int c = 0; c < nchunks; ++c) {
        // <=3 outstanding -> chunk c has landed in LDS. memory clobber pins
        // the ds_read below this wait.
        asm volatile("s_waitcnt vmcnt(3)" ::: "memory");
        vf4 e = bufs[(c & (DEPTH - 1)) * CHUNK + lane];  // ds_read_b128
        int x = ev_idx(e);
        atomicOr(&bm[x >> 5], 1u << (x & 31));
        // refill same buffer slot with chunk c+DEPTH (DMA data can't return
        // before the in-order ds_read above has executed)
        if (c + DEPTH < nchunks)
            async_ev16(base + (c + DEPTH) * CHUNK, &bufs[(c & (DEPTH - 1)) * CHUNK]);
    }

    // generic tail (0 iterations for N=2^24)
    const int done = GRID * WAVES * per_wave;
    for (int i = done + blockIdx.x * BLK + threadIdx.x; i < n; i += GRID * BLK) {
        vf4 e = events[i];
        int x = ev_idx(e);
        atomicOr(&bm[x >> 5], 1u << (x & 31));
    }

    __syncthreads();
    // Aggregated wave-contiguous merge (R3/R8-proven cheap, line-batched at L2)
    for (int w = threadIdx.x; w < NWORDS; w += BLK) {
        unsigned int v = bm[w];
        if (v) atomicOr(&gbm[w], v);
    }
}

// Bit bitmap -> float output. Thread t handles one float4; 8 lanes share one
// bitmap word (broadcast). Writes every element of d_out: no memset needed.
__global__ void __launch_bounds__(256)
expand_kernel(const unsigned int* __restrict__ gbm, float* __restrict__ out) {
    int t = blockIdx.x * 256 + threadIdx.x;   // [0, NVOX/4)
    unsigned int wv = gbm[t >> 3];
    int sh = (t & 7) * 4;
    vf4 v;
    v.x = (wv >> (sh + 0)) & 1u ? 1.0f : 0.0f;
    v.y = (wv >> (sh + 1)) & 1u ? 1.0f : 0.0f;
    v.z = (wv >> (sh + 2)) & 1u ? 1.0f : 0.0f;
    v.w = (wv >> (sh + 3)) & 1u ? 1.0f : 0.0f;
    ((vf4*)out)[t] = v;
}

extern "C" void kernel_launch(void* const* d_in, const int* in_sizes, int n_in,
                              void* d_out, int out_size, void* d_ws, size_t ws_size,
                              hipStream_t stream) {
    const vf4* events = (const vf4*)d_in[0];
    float* out = (float*)d_out;
    int n = in_sizes[0] / 4;                   // in_sizes[0] = N*4 flat elems

    unsigned int* gbm = (unsigned int*)d_ws;   // 76.8 KB global bitmap

    // ws is re-poisoned to 0xAA each call — zero the bitmap (~1 us).
    hipMemsetAsync(gbm, 0, NWORDS * sizeof(unsigned int), stream);

    event_bitmap_dma<<<GRID, BLK, 0, stream>>>(events, gbm, n);
    expand_kernel<<<NVOX / 4 / 256, 256, 0, stream>>>(gbm, out);
}